// Round 15
// baseline (30.076 us; speedup 1.0000x reference)
//
#include <hip/hip_runtime.h>
#include <hip/hip_bf16.h>

#define IN_F 8192
#define OUT_F 8192
#define BATCH 64
#define KSPLIT 8

typedef __attribute__((ext_vector_type(8))) short  bf16x8_t;  // 8 bf16 (4 VGPRs)
typedef __attribute__((ext_vector_type(8))) ushort u16x8_t;   // 16B store unit
typedef __attribute__((ext_vector_type(4))) float  f32x4_t;   // MFMA accumulator

// ---------------------------------------------------------------------------
// Fused stage-A: x fp32 -> bf16 LDS + MFMA GEMM + in-block K-pair combine.
// Grid: 32 N-tiles x 8 K-splits = 256 blocks x 512 thr (1 block/CU).
// Waves: 4 col-groups (cg) x 2 K-groups (kg). Wave tile: 64 rows x 64 cols
// x 512 K (4 mi x 4 nj) -> per group: 16 ds_read_b128 feed 64 MFMAs
// (2x better af:MFMA amortization than 32-col waves; block LDS reads halve).
// Dequant still exactly once per qword chip-wide (K-split, not M-split).
// Epilogue: kg=1 writes acc to padded LDS, kg=0 combines + stores bf16
// partials; wol_reduce sums 8 K-splits + bias.
// ---------------------------------------------------------------------------
__global__ void __launch_bounds__(512, 2)
wol_mfma(const float*  __restrict__ x,
         const int*    __restrict__ qw,
         const int*    __restrict__ qz,
         const float*  __restrict__ sc,
         ushort*       __restrict__ part) {
    const int nt   = blockIdx.x & 31;
    const int ks   = blockIdx.x >> 5;           // 0..7
    const int wid  = threadIdx.x >> 6;
    const int lane = threadIdx.x & 63;
    const int ln   = lane & 15;
    const int kb   = lane >> 4;                 // k-subblock 0..3
    const int cg   = wid & 3;                   // col-group 0..3
    const int kg   = wid >> 2;                  // K-group 0..1
    const int colbase = nt * 256 + cg * 64;     // wave's 64 columns
    const int k0      = ks * 1024;              // block K range
    const int kwave   = k0 + kg * 512;          // wave K range (4 groups)
    const int gbaseW  = kwave >> 7;
    const int qrowbW  = kwave >> 3;             // 64 qrows per wave

    // ---- group-0 prefetch (in flight across LDS staging + barrier) ----
    unsigned qc[4][4]; float svc[4]; unsigned zwc[4];
#pragma unroll
    for (int kt = 0; kt < 4; ++kt)
#pragma unroll
        for (int nj = 0; nj < 4; ++nj)
            qc[kt][nj] = (unsigned)qw[(size_t)(qrowbW + kt * 4 + kb) * OUT_F +
                                      colbase + nj * 16 + ln];
#pragma unroll
    for (int nj = 0; nj < 4; ++nj) {
        const int c = colbase + nj * 16 + ln;
        svc[nj] = sc[gbaseW * OUT_F + c];
        zwc[nj] = (unsigned)qz[gbaseW * (OUT_F / 8) + (c >> 3)];
    }
    __builtin_amdgcn_sched_barrier(0);          // pin group-0 loads here

    // ---- fused staging: x fp32 -> bf16 swizzled row-major LDS (128 KB) ----
    __shared__ ushort lds_x[128 * 64 * 8];
    {
#pragma unroll
        for (int i = 0; i < 16; ++i) {
            const int idx = i * 512 + (int)threadIdx.x;  // 8192 frags
            const int row = idx >> 7;                    // 0..63
            const int k8l = idx & 127;                   // 0..127
            const float4* sp = (const float4*)&x[(size_t)row * IN_F + k0 + k8l * 8];
            const float4 a = sp[0], b = sp[1];
            const float f[8] = {a.x, a.y, a.z, a.w, b.x, b.y, b.z, b.w};
            union { ushort u[8]; bf16x8_t v; } o;
#pragma unroll
            for (int j = 0; j < 8; ++j) {
                __hip_bfloat16 hb = __float2bfloat16(f[j]);
                o.u[j] = *reinterpret_cast<ushort*>(&hb);
            }
            unsigned byteoff = (unsigned)(row * 2048 + k8l * 16);
            byteoff ^= (unsigned)((row & 7) << 4);       // T2 XOR swizzle
            *(bf16x8_t*)((char*)lds_x + byteoff) = o.v;
        }
    }
    __syncthreads();

    const unsigned xorv = (unsigned)((ln & 7) << 4);     // af-read swizzle

    f32x4_t acc[4][4];
#pragma unroll
    for (int mi = 0; mi < 4; ++mi)
#pragma unroll
        for (int nj = 0; nj < 4; ++nj) acc[mi][nj] = (f32x4_t)0.0f;

#pragma unroll 1
    for (int g = 0; g < 4; ++g) {               // wave's 4 quant groups
        // ---- prefetch group g+1 BEFORE computing group g, pinned ----
        unsigned qn[4][4]; float svn[4]; unsigned zwn[4];
        if (g < 3) {
            const int qrow1 = qrowbW + (g + 1) * 16;
#pragma unroll
            for (int kt = 0; kt < 4; ++kt)
#pragma unroll
                for (int nj = 0; nj < 4; ++nj)
                    qn[kt][nj] = (unsigned)qw[(size_t)(qrow1 + kt * 4 + kb) * OUT_F +
                                              colbase + nj * 16 + ln];
#pragma unroll
            for (int nj = 0; nj < 4; ++nj) {
                const int c = colbase + nj * 16 + ln;
                svn[nj] = sc[(gbaseW + g + 1) * OUT_F + c];
                zwn[nj] = (unsigned)qz[(gbaseW + g + 1) * (OUT_F / 8) + (c >> 3)];
            }
            __builtin_amdgcn_sched_barrier(0);  // loads stay ABOVE the compute
        }

        float s[4], dz[4];
#pragma unroll
        for (int nj = 0; nj < 4; ++nj) {
            const unsigned zp = ((zwc[nj] >> ((ln & 7) * 4)) + 1u) & 15u;  // zp-1 stored
            s[nj]  = svc[nj];
            dz[nj] = -(float)zp * svc[nj];      // w = nib*s + dz
        }

#pragma unroll
        for (int kt = 0; kt < 4; ++kt) {        // 4 K-steps of 32
            // local k8 within block: kg*64 + g*16 + kt*4 + kb
            const unsigned kbyte =
                (unsigned)((kg * 64 + g * 16 + kt * 4 + kb) * 16) ^ xorv;
            bf16x8_t af[4];
#pragma unroll
            for (int mi = 0; mi < 4; ++mi)
                af[mi] = *(const bf16x8_t*)((const char*)lds_x +
                            (unsigned)((mi * 16 + ln) * 2048) + kbyte);
#pragma unroll
            for (int nj = 0; nj < 4; ++nj) {
                const unsigned qv  = qc[kt][nj];
                const unsigned qlo = qv & 0x0F0F0F0Fu;         // nibbles 0,2,4,6
                const unsigned qhi = (qv >> 4) & 0x0F0F0F0Fu;  // nibbles 1,3,5,7
                union { ushort u[8]; bf16x8_t v; } bu;
#pragma unroll
                for (int b = 0; b < 4; ++b) {
                    const float fe = (float)((qlo >> (8 * b)) & 0xFFu);  // v_cvt_f32_ubyteN
                    const float fo = (float)((qhi >> (8 * b)) & 0xFFu);
                    const float we = fe * s[nj] + dz[nj];
                    const float wo = fo * s[nj] + dz[nj];
                    __hip_bfloat16 he = __float2bfloat16(we);
                    __hip_bfloat16 ho = __float2bfloat16(wo);
                    bu.u[2 * b]     = *reinterpret_cast<ushort*>(&he);
                    bu.u[2 * b + 1] = *reinterpret_cast<ushort*>(&ho);
                }
#pragma unroll
                for (int mi = 0; mi < 4; ++mi)
                    acc[mi][nj] = __builtin_amdgcn_mfma_f32_16x16x32_bf16(
                        af[mi], bu.v, acc[mi][nj], 0, 0, 0);
            }
        }

        if (g < 3) {                            // rotate prefetch buffers
#pragma unroll
            for (int kt = 0; kt < 4; ++kt)
#pragma unroll
                for (int nj = 0; nj < 4; ++nj) qc[kt][nj] = qn[kt][nj];
#pragma unroll
            for (int nj = 0; nj < 4; ++nj) { svc[nj] = svn[nj]; zwc[nj] = zwn[nj]; }
        }
    }

    // ---- in-block combine of the two K-groups via padded LDS ----
    __syncthreads();                            // all lds_x reads done
    float* red = (float*)lds_x;                 // [4 cg][64 lane][68 floats]
    if (kg == 1) {
#pragma unroll
        for (int mi = 0; mi < 4; ++mi)
#pragma unroll
            for (int nj = 0; nj < 4; ++nj)
                *(f32x4_t*)&red[(cg * 64 + lane) * 68 + (mi * 4 + nj) * 4] =
                    acc[mi][nj];
    }
    __syncthreads();
    if (kg == 1) return;

    // ---- kg=0: combine + bf16 fragment-major partial store (128 B) ----
    union { ushort u[64]; u16x8_t v8[8]; } ob;
#pragma unroll
    for (int mi = 0; mi < 4; ++mi)
#pragma unroll
        for (int nj = 0; nj < 4; ++nj) {
            const f32x4_t r =
                *(const f32x4_t*)&red[(cg * 64 + lane) * 68 + (mi * 4 + nj) * 4];
#pragma unroll
            for (int j = 0; j < 4; ++j) {
                const float v = acc[mi][nj][j] + r[j];
                __hip_bfloat16 h = __float2bfloat16(v);
                ob.u[(mi * 4 + nj) * 4 + j] = *reinterpret_cast<ushort*>(&h);
            }
        }
    u16x8_t* pb = (u16x8_t*)part + ((size_t)(ks * 32 + nt) * 256 + threadIdx.x) * 8;
#pragma unroll
    for (int i = 0; i < 8; ++i) pb[i] = ob.v8[i];
}

// ---------------------------------------------------------------------------
// Stage B: sum 8 bf16 K-split partials (fragment layout) + bias -> out.
// Each output element written exactly once. 65536 threads.
// ---------------------------------------------------------------------------
__global__ void __launch_bounds__(256)
wol_reduce(const ushort* __restrict__ part,
           const float*  __restrict__ bias,
           float* __restrict__ out) {
    const int u    = blockIdx.x * 256 + threadIdx.x;
    const int v8   = u & 7;              // which ushort8 of the thread's 64
    const int tidA = (u >> 3) & 255;     // stage-A kg0 thread id
    const int nt   = u >> 11;            // stage-A N-tile

    float s[8];
#pragma unroll
    for (int e = 0; e < 8; ++e) s[e] = 0.0f;
#pragma unroll
    for (int ks = 0; ks < KSPLIT; ++ks) {
        const u16x8_t p = *((const u16x8_t*)part +
                            (((size_t)(ks * 32 + nt) * 256 + tidA) * 8 + v8));
#pragma unroll
        for (int e = 0; e < 8; ++e) {
            union { unsigned b; float f; } cv;
            cv.b = ((unsigned)(ushort)p[e]) << 16;   // bf16 -> f32 exact
            s[e] += cv.f;
        }
    }

    const int cg = tidA >> 6, lane = tidA & 63;
    const int ln = lane & 15, kb = lane >> 4;
#pragma unroll
    for (int e = 0; e < 8; ++e) {
        const int idx = v8 * 8 + e;                  // (mi*4+nj)*4 + j
        const int mi = idx >> 4, nj = (idx >> 2) & 3, j = idx & 3;
        const int row = mi * 16 + kb * 4 + j;
        const int col = nt * 256 + cg * 64 + nj * 16 + ln;
        out[(size_t)row * OUT_F + col] = s[e] + bias[col];
    }
}

extern "C" void kernel_launch(void* const* d_in, const int* in_sizes, int n_in,
                              void* d_out, int out_size, void* d_ws, size_t ws_size,
                              hipStream_t stream) {
    const float* x    = (const float*)d_in[0];
    const int*   qw   = (const int*)d_in[1];
    const int*   qz   = (const int*)d_in[2];
    const float* sc   = (const float*)d_in[3];
    const float* bias = (const float*)d_in[4];
    float* out = (float*)d_out;

    ushort* prt = (ushort*)d_ws;                 // 8 MiB bf16 partials

    (void)in_sizes; (void)n_in; (void)ws_size; (void)out_size;

    wol_mfma<<<256, 512, 0, stream>>>(x, qw, qz, sc, prt);
    wol_reduce<<<256, 256, 0, stream>>>(prt, bias, out);
}

// Round 16
// 25.278 us; speedup vs baseline: 1.1898x; 1.1898x over previous
//
#include <hip/hip_runtime.h>
#include <hip/hip_bf16.h>

#define IN_F 8192
#define OUT_F 8192
#define BATCH 64
#define KSPLIT 8

typedef __attribute__((ext_vector_type(8))) _Float16 f16x8_t;  // 8 f16 (4 VGPRs)
typedef __attribute__((ext_vector_type(2))) _Float16 f16x2_t;  // packed pair
typedef __attribute__((ext_vector_type(8))) ushort   u16x8_t;  // 16B store unit
typedef __attribute__((ext_vector_type(4))) float    f32x4_t;  // MFMA accumulator

// ---------------------------------------------------------------------------
// Fused stage-A: x fp32 -> f16 LDS (k-permuted) + MFMA f16 GEMM + partials.
// Grid: 32 N-tiles x 8 K-splits = 256 blocks x 512 thr (1 block/CU).
// Dequant: int4->f16 magic trick:  r = ((q>>4i)&0x000F000F)|0x64006400
// gives packed (1024+n_i, 1024+n_{i+4}); w = (r - (1024+zp)) * s in packed
// f16 (pk_add exact, pk_mul single-rounding).  ~15 VALU/qword vs ~25 for
// the old byte-cvt->f32-fma->bf16 chain, and zero sub-dword packing.
// Pair order permutes k within each 8-chunk as [0,4,1,5,2,6,3,7]; the LDS
// x staging writes the SAME permutation -> dot product unchanged.
// Everything else identical to R14 (the 26.8us anchor).
// ---------------------------------------------------------------------------
__global__ void __launch_bounds__(512, 4)
wol_mfma(const float*  __restrict__ x,
         const int*    __restrict__ qw,
         const int*    __restrict__ qz,
         const float*  __restrict__ sc,
         ushort*       __restrict__ part) {
    const int nt   = blockIdx.x & 31;
    const int ks   = blockIdx.x >> 5;           // 0..7
    const int wid  = threadIdx.x >> 6;
    const int lane = threadIdx.x & 63;
    const int ln   = lane & 15;
    const int kb   = lane >> 4;                 // k-subblock 0..3
    const int colbase = nt * 256 + wid * 32;    // wave's 32 columns
    const int k0      = ks * 1024;              // block K range (8 groups)
    const int gbase   = k0 >> 7;
    const int qrowb   = k0 >> 3;                // 128 qrows per block

    // ---- group-0 prefetch (in flight across LDS staging + barrier) ----
    unsigned qc[4][2]; float svc[2]; unsigned zwc[2];
#pragma unroll
    for (int kt = 0; kt < 4; ++kt)
#pragma unroll
        for (int nj = 0; nj < 2; ++nj)
            qc[kt][nj] = (unsigned)qw[(size_t)(qrowb + kt * 4 + kb) * OUT_F +
                                      colbase + nj * 16 + ln];
#pragma unroll
    for (int nj = 0; nj < 2; ++nj) {
        const int c = colbase + nj * 16 + ln;
        svc[nj] = sc[gbase * OUT_F + c];
        zwc[nj] = (unsigned)qz[gbase * (OUT_F / 8) + (c >> 3)];
    }
    __builtin_amdgcn_sched_barrier(0);          // pin group-0 loads here

    // ---- fused staging: x fp32 -> f16, k-permuted, swizzled LDS (128KB) ----
    __shared__ ushort lds_x[128 * 64 * 8];
    {
        const int perm[8] = {0, 4, 1, 5, 2, 6, 3, 7};   // frag j -> source k
#pragma unroll
        for (int i = 0; i < 16; ++i) {
            const int idx = i * 512 + (int)threadIdx.x;  // 8192 frags
            const int row = idx >> 7;                    // 0..63
            const int k8l = idx & 127;                   // 0..127
            const float4* sp = (const float4*)&x[(size_t)row * IN_F + k0 + k8l * 8];
            const float4 a = sp[0], b = sp[1];
            const float f[8] = {a.x, a.y, a.z, a.w, b.x, b.y, b.z, b.w};
            union { ushort u[8]; u16x8_t v; } o;
#pragma unroll
            for (int j = 0; j < 8; ++j) {
                const _Float16 h = (_Float16)f[perm[j]];
                o.u[j] = *(const ushort*)&h;
            }
            unsigned byteoff = (unsigned)(row * 2048 + k8l * 16);
            byteoff ^= (unsigned)((row & 7) << 4);       // T2 XOR swizzle
            *(u16x8_t*)((char*)lds_x + byteoff) = o.v;
        }
    }
    __syncthreads();

    const unsigned xorv = (unsigned)((ln & 7) << 4);     // af-read swizzle

    f32x4_t acc[4][2];
#pragma unroll
    for (int mi = 0; mi < 4; ++mi)
#pragma unroll
        for (int nj = 0; nj < 2; ++nj) acc[mi][nj] = (f32x4_t)0.0f;

#pragma unroll 1
    for (int g = 0; g < 8; ++g) {               // 8 quant groups of 128 K
        // ---- prefetch group g+1 BEFORE computing group g, pinned ----
        unsigned qn[4][2]; float svn[2]; unsigned zwn[2];
        if (g < 7) {
            const int qrow1 = qrowb + (g + 1) * 16;
#pragma unroll
            for (int kt = 0; kt < 4; ++kt)
#pragma unroll
                for (int nj = 0; nj < 2; ++nj)
                    qn[kt][nj] = (unsigned)qw[(size_t)(qrow1 + kt * 4 + kb) * OUT_F +
                                              colbase + nj * 16 + ln];
#pragma unroll
            for (int nj = 0; nj < 2; ++nj) {
                const int c = colbase + nj * 16 + ln;
                svn[nj] = sc[(gbase + g + 1) * OUT_F + c];
                zwn[nj] = (unsigned)qz[(gbase + g + 1) * (OUT_F / 8) + (c >> 3)];
            }
            __builtin_amdgcn_sched_barrier(0);  // loads stay ABOVE the compute
        }

        // per-group packed f16 constants: c2 = -(1024+zp) (exact), s2 = s
        f16x2_t c2[2], s2[2];
#pragma unroll
        for (int nj = 0; nj < 2; ++nj) {
            const unsigned zp = ((zwc[nj] >> ((ln & 7) * 4)) + 1u) & 15u;  // zp-1 stored
            const _Float16 hc = (_Float16)(-(float)(1024u + zp));
            const _Float16 hs = (_Float16)svc[nj];
            c2[nj][0] = hc; c2[nj][1] = hc;
            s2[nj][0] = hs; s2[nj][1] = hs;
        }

#pragma unroll
        for (int kt = 0; kt < 4; ++kt) {        // 4 K-steps of 32
            const unsigned kbyte = (unsigned)(g * 256 + kt * 64 + kb * 16) ^ xorv;
            f16x8_t af[4];
#pragma unroll
            for (int mi = 0; mi < 4; ++mi)
                af[mi] = *(const f16x8_t*)((const char*)lds_x +
                            (unsigned)((mi * 16 + ln) * 2048) + kbyte);
#pragma unroll
            for (int nj = 0; nj < 2; ++nj) {
                const unsigned qv = qc[kt][nj];
                // int4 -> f16 magic unpack: pairs (n_i, n_{i+4}) at +1024
                const unsigned r0 = ( qv        & 0x000F000Fu) | 0x64006400u;
                const unsigned r1 = ((qv >> 4)  & 0x000F000Fu) | 0x64006400u;
                const unsigned r2 = ((qv >> 8)  & 0x000F000Fu) | 0x64006400u;
                const unsigned r3 = ((qv >> 12) & 0x000F000Fu) | 0x64006400u;
                union { unsigned u[4]; f16x8_t v; } bu;
                union { unsigned u; f16x2_t h; } t0, t1, t2, t3;
                t0.u = r0; t1.u = r1; t2.u = r2; t3.u = r3;
                f16x2_t w0 = (t0.h + c2[nj]) * s2[nj];   // pk_add exact, pk_mul
                f16x2_t w1 = (t1.h + c2[nj]) * s2[nj];
                f16x2_t w2 = (t2.h + c2[nj]) * s2[nj];
                f16x2_t w3 = (t3.h + c2[nj]) * s2[nj];
                bu.u[0] = *(const unsigned*)&w0;
                bu.u[1] = *(const unsigned*)&w1;
                bu.u[2] = *(const unsigned*)&w2;
                bu.u[3] = *(const unsigned*)&w3;
#pragma unroll
                for (int mi = 0; mi < 4; ++mi)
                    acc[mi][nj] = __builtin_amdgcn_mfma_f32_16x16x32_f16(
                        af[mi], bu.v, acc[mi][nj], 0, 0, 0);
            }
        }

        if (g < 7) {                            // rotate prefetch buffers
#pragma unroll
            for (int kt = 0; kt < 4; ++kt)
#pragma unroll
                for (int nj = 0; nj < 2; ++nj) qc[kt][nj] = qn[kt][nj];
#pragma unroll
            for (int nj = 0; nj < 2; ++nj) { svc[nj] = svn[nj]; zwc[nj] = zwn[nj]; }
        }
    }

    // ---- epilogue: bf16 fragment-major partials, one 64B store/thread ----
    union { ushort u[32]; u16x8_t v8[4]; } ob;
#pragma unroll
    for (int mi = 0; mi < 4; ++mi)
#pragma unroll
        for (int nj = 0; nj < 2; ++nj)
#pragma unroll
            for (int j = 0; j < 4; ++j) {
                __hip_bfloat16 h = __float2bfloat16(acc[mi][nj][j]);
                ob.u[(mi * 2 + nj) * 4 + j] = *reinterpret_cast<ushort*>(&h);
            }
    u16x8_t* pb = (u16x8_t*)part + ((size_t)(ks * 32 + nt) * 512 + threadIdx.x) * 4;
#pragma unroll
    for (int i = 0; i < 4; ++i) pb[i] = ob.v8[i];
}

// ---------------------------------------------------------------------------
// Stage B: sum 8 bf16 K-split partials (fragment layout) + bias -> out.
// Each output element written exactly once. 65536 threads.
// ---------------------------------------------------------------------------
__global__ void __launch_bounds__(256)
wol_reduce(const ushort* __restrict__ part,
           const float*  __restrict__ bias,
           float* __restrict__ out) {
    const int u   = blockIdx.x * 256 + threadIdx.x;
    const int v8  = u & 3;               // which ushort8 of the thread's 32
    const int tid = (u >> 2) & 511;      // stage-A thread id
    const int nt  = u >> 11;             // stage-A N-tile

    float s[8];
#pragma unroll
    for (int e = 0; e < 8; ++e) s[e] = 0.0f;
#pragma unroll
    for (int ks = 0; ks < KSPLIT; ++ks) {
        const u16x8_t p = *((const u16x8_t*)part +
                            (((size_t)(ks * 32 + nt) * 512 + tid) * 4 + v8));
#pragma unroll
        for (int e = 0; e < 8; ++e) {
            union { unsigned b; float f; } cv;
            cv.b = ((unsigned)(ushort)p[e]) << 16;   // bf16 -> f32 exact
            s[e] += cv.f;
        }
    }

    const int wid = tid >> 6, lane = tid & 63;
    const int ln = lane & 15, kb = lane >> 4;
#pragma unroll
    for (int e = 0; e < 8; ++e) {
        const int idx = v8 * 8 + e;                  // (mi*2+nj)*4 + j
        const int mi = idx >> 3, nj = (idx >> 2) & 1, j = idx & 3;
        const int row = mi * 16 + kb * 4 + j;
        const int col = nt * 256 + wid * 32 + nj * 16 + ln;
        out[(size_t)row * OUT_F + col] = s[e] + bias[col];
    }
}

extern "C" void kernel_launch(void* const* d_in, const int* in_sizes, int n_in,
                              void* d_out, int out_size, void* d_ws, size_t ws_size,
                              hipStream_t stream) {
    const float* x    = (const float*)d_in[0];
    const int*   qw   = (const int*)d_in[1];
    const int*   qz   = (const int*)d_in[2];
    const float* sc   = (const float*)d_in[3];
    const float* bias = (const float*)d_in[4];
    float* out = (float*)d_out;

    ushort* prt = (ushort*)d_ws;                 // 8 MiB bf16 partials

    (void)in_sizes; (void)n_in; (void)ws_size; (void)out_size;

    wol_mfma<<<256, 512, 0, stream>>>(x, qw, qz, sc, prt);
    wol_reduce<<<256, 256, 0, stream>>>(prt, bias, out);
}